// Round 7
// baseline (876.905 us; speedup 1.0000x reference)
//
#include <hip/hip_runtime.h>

typedef unsigned short u16;
typedef __attribute__((ext_vector_type(8))) short s8v;   // 8 bf16 (4 VGPRs) — MFMA A/B frag
typedef __attribute__((ext_vector_type(4))) float f4v;   // 4 fp32 — MFMA C/D frag

#define NN 16384
#define EE 262144
#define ET (EE + NN)      // 278528 = 4352 * 64
#define NTILES (ET / 64)  // 4352

__device__ __forceinline__ float bfu(u16 h){ return __uint_as_float((unsigned)h << 16); }
__device__ __forceinline__ u16 f2bf(float f){
  unsigned u = __float_as_uint(f);
  unsigned r = u + 0x7FFFu + ((u >> 16) & 1u);   // RNE
  return (u16)(r >> 16);
}
__device__ __forceinline__ float ldf(const void* p, size_t i, int isbf){
  return isbf ? bfu(((const u16*)p)[i]) : ((const float*)p)[i];
}
__device__ __forceinline__ float gelu_f(float x){ return 0.5f*x*(1.0f+erff(x*0.7071067811865475f)); }

__device__ __forceinline__ uint4 load8bf(const void* p, size_t eoff, int isbf){
  if (isbf) return *(const uint4*)((const u16*)p + eoff);
  const float* f = (const float*)p + eoff;
  uint4 r;
  r.x = (unsigned)f2bf(f[0]) | ((unsigned)f2bf(f[1])<<16);
  r.y = (unsigned)f2bf(f[2]) | ((unsigned)f2bf(f[3])<<16);
  r.z = (unsigned)f2bf(f[4]) | ((unsigned)f2bf(f[5])<<16);
  r.w = (unsigned)f2bf(f[6]) | ((unsigned)f2bf(f[7])<<16);
  return r;
}

// ---------------- dtype detector ----------------
__global__ void k_detect(const void* nf, int* flag)
{
  int t = threadIdx.x;
  const float* f = (const float*)nf;
  int cnt = 0;
  for (int i = t; i < 4096; i += 256) {
    float a = fabsf(f[i]);
    if (a > 1e-5f && a < 100.0f) cnt++;   // NaN compares false
  }
  __shared__ int s[256];
  s[t] = cnt; __syncthreads();
  for (int st = 128; st > 0; st >>= 1) { if (t < st) s[t] += s[t+st]; __syncthreads(); }
  if (t == 0) *flag = (s[0] < 2048) ? 1 : 0;
}

// ---------------- MFMA GEMM 128x128 tiles: C[M,N] = A @ B^T (+bias)(+gelu), dual-B split ----------------
template<int ACT, int CFMT>
__global__ __launch_bounds__(256)
void mfma_gemm(const void* __restrict__ A, int a_fmt,
               const void* __restrict__ B1, size_t b1off,
               const void* __restrict__ B2, size_t b2off, int nsplit,
               const void* __restrict__ bias1, const void* __restrict__ bias2,
               size_t bioff, int has_bias,
               void* __restrict__ C, int M, int N, int K,
               const int* __restrict__ dflag)
{
  int isbf = *dflag;
  int af = (a_fmt == 2) ? isbf : a_fmt;
  __shared__ u16 As[128*40];
  __shared__ u16 Bs[128*40];
  int bm = blockIdx.y*128, bn = blockIdx.x*128;
  int t = threadIdx.x;
  int w = t>>6, lane = t&63, l4 = lane&15, quad = lane>>4;
  int wm = w>>1, wn = w&1;
  f4v zero = {0.f,0.f,0.f,0.f};
  f4v acc[4][4];
  #pragma unroll
  for (int i=0;i<4;i++)
    #pragma unroll
    for (int j=0;j<4;j++) acc[i][j] = zero;

  for (int k0 = 0; k0 < K; k0 += 32) {
    __syncthreads();
    #pragma unroll
    for (int it = 0; it < 2; ++it) {
      int sid = t + it*256;
      int row = sid >> 2, sk = sid & 3;
      *(uint4*)&As[row*40 + sk*8] = load8bf(A, (size_t)(bm+row)*K + k0 + sk*8, af);
      int col = bn + row;
      uint4 vb;
      if (col < nsplit) vb = load8bf(B1, b1off + (size_t)col*K + k0 + sk*8, isbf);
      else              vb = load8bf(B2, b2off + (size_t)(col-nsplit)*K + k0 + sk*8, isbf);
      *(uint4*)&Bs[row*40 + sk*8] = vb;
    }
    __syncthreads();
    s8v a[4], b[4];
    #pragma unroll
    for (int i=0;i<4;i++) a[i] = *(const s8v*)&As[(wm*64 + i*16 + l4)*40 + quad*8];
    #pragma unroll
    for (int j=0;j<4;j++) b[j] = *(const s8v*)&Bs[(wn*64 + j*16 + l4)*40 + quad*8];
    #pragma unroll
    for (int i=0;i<4;i++)
      #pragma unroll
      for (int j=0;j<4;j++)
        acc[i][j] = __builtin_amdgcn_mfma_f32_16x16x32_bf16(a[i], b[j], acc[i][j], 0,0,0);
  }
  #pragma unroll
  for (int i=0;i<4;i++)
    #pragma unroll
    for (int j=0;j<4;j++) {
      int col = bn + wn*64 + j*16 + l4;
      float bv = 0.f;
      if (has_bias) bv = (col < nsplit) ? ldf(bias1, bioff + col, isbf)
                                        : ldf(bias2, bioff + col - nsplit, isbf);
      #pragma unroll
      for (int r=0;r<4;r++) {
        int row = bm + wm*64 + i*16 + quad*4 + r;
        float v = acc[i][j][r] + bv;
        if (ACT==1) v = gelu_f(v);
        if (CFMT==1) ((u16*)C)[(size_t)row*N + col] = f2bf(v);
        else         ((float*)C)[(size_t)row*N + col] = v;
      }
    }
}

// ---------------- CSR build ----------------
__global__ void k_count(const int* __restrict__ dst, int* __restrict__ deg)
{
  int e = blockIdx.x*256 + threadIdx.x;
  if (e >= ET) return;
  int d = (e < EE) ? dst[e] : (e - EE);
  atomicAdd(&deg[d], 1);
}

__global__ void k_scan(const int* __restrict__ deg, int* __restrict__ rowstart)
{
  __shared__ int csum[256];
  int t = threadIdx.x;
  int s = 0;
  for (int i=0;i<64;i++) s += deg[t*64+i];
  csum[t] = s;
  __syncthreads();
  if (t == 0) {
    int r = 0;
    for (int i=0;i<256;i++){ int v = csum[i]; csum[i] = r; r += v; }
    rowstart[NN] = r;
  }
  __syncthreads();
  int b = csum[t];
  for (int i=0;i<64;i++){ rowstart[t*64+i] = b; b += deg[t*64+i]; }
}

__global__ void k_scatter(const int* __restrict__ dst, const int* __restrict__ src,
                          const int* __restrict__ rowstart, int* __restrict__ fill,
                          int* __restrict__ csr, int* __restrict__ srcof, int* __restrict__ dstof)
{
  int e = blockIdx.x*256 + threadIdx.x;
  if (e >= ET) return;
  int d = (e < EE) ? dst[e] : (e - EE);
  int pos = rowstart[d] + atomicAdd(&fill[d], 1);
  csr[pos] = e;
  srcof[pos] = (e < EE) ? src[e] : (e - EE);
  dstof[pos] = d;
}

__global__ void k_loopmean(const int* __restrict__ csr, const int* __restrict__ rowstart,
                           const void* __restrict__ edge_attr, u16* __restrict__ loopmean,
                           const int* __restrict__ dflag)
{
  int isbf = *dflag;
  int n = blockIdx.x, j = threadIdx.x;   // 64 threads
  int s = rowstart[n], e1 = rowstart[n+1];
  float sum = 0.f; int cnt = 0;
  for (int p = s; p < e1; ++p) {
    int eid = csr[p];
    if (eid < EE) { sum += ldf(edge_attr, (size_t)eid*64 + j, isbf); cnt++; }
  }
  loopmean[(size_t)n*64 + j] = f2bf(sum / (float)max(cnt, 1));
}

// Wc[l] = lin_edge_w[l] ([256,128]) @ init_edge_w ([128,64]) -> [L,256,64] bf16
__global__ void k_wc(const void* __restrict__ We, const void* __restrict__ iew,
                     u16* __restrict__ Wcb, const int* __restrict__ dflag)
{
  int isbf = *dflag;
  int idx = blockIdx.x*256 + threadIdx.x;    // 32768
  int j = idx & 63, c = (idx >> 6) & 255, l = idx >> 14;
  float s = 0.f;
  for (int k=0;k<128;k++) s += ldf(We, ((size_t)l*256 + c)*128 + k, isbf) * ldf(iew, (size_t)k*64 + j, isbf);
  Wcb[idx] = f2bf(s);
}

// ---------------- edge logits in CSR order (no inner barriers, direct B-frag gathers) ----------------
// Lane owns position p = e0 + w*16 + l4 (4 lanes per edge, one per quad). MFMA: D[ch][edge], edge = l4.
__global__ __launch_bounds__(256)
void k_elogits(const int* __restrict__ csr, const int* __restrict__ srcof, const int* __restrict__ dstof,
               const u16* __restrict__ Wcb, const u16* __restrict__ xlr,
               const void* __restrict__ edge_attr, const u16* __restrict__ loopmean,
               const void* __restrict__ att, size_t att_off,
               float* __restrict__ logits, const int* __restrict__ dflag)
{
  int isbf = *dflag;
  __shared__ u16 WcF[32*64*8];    // 32 A-frags x 64 lanes x 8 bf16 (frag order, b128 conflict-free)
  __shared__ float satt[256];

  int t = threadIdx.x;
  int w = t>>6, lane = t&63, l4 = lane&15, quad = lane>>4;

  satt[t] = ldf(att, att_off + t, isbf);
  #pragma unroll
  for (int f = 0; f < 8; ++f) {
    int fr = w + f*4;              // 0..31
    int i = fr >> 1, ks = fr & 1;
    *(uint4*)&WcF[(fr*64 + lane)*8] = *(const uint4*)&Wcb[(size_t)(16*i + l4)*64 + ks*32 + quad*8];
  }
  __syncthreads();                 // one-time; loop below is barrier-free

  f4v zero = {0.f,0.f,0.f,0.f};
  for (int tile = blockIdx.x; tile < NTILES; tile += gridDim.x) {
    int p  = tile*64 + w*16 + l4;  // CSR position this lane serves
    int eid = csr[p];
    int sn = srcof[p], dn = dstof[p];

    // B-frags: 8 attr channels at k = quad*8 and 32+quad*8 of this edge
    uint4 b0u, b1u;
    if (eid < EE) {
      b0u = load8bf(edge_attr, (size_t)eid*64 + quad*8,      isbf);
      b1u = load8bf(edge_attr, (size_t)eid*64 + 32 + quad*8, isbf);
    } else {
      b0u = *(const uint4*)&loopmean[(size_t)(eid-EE)*64 + quad*8];
      b1u = *(const uint4*)&loopmean[(size_t)(eid-EE)*64 + 32 + quad*8];
    }
    s8v b0 = *(const s8v*)&b0u;
    s8v b1 = *(const s8v*)&b1u;

    f4v acc[16];
    #pragma unroll
    for (int i=0;i<16;++i){
      s8v a0 = *(const s8v*)&WcF[((2*i  )*64 + lane)*8];
      s8v a1 = *(const s8v*)&WcF[((2*i+1)*64 + lane)*8];
      acc[i] = __builtin_amdgcn_mfma_f32_16x16x32_bf16(a0, b0, zero, 0,0,0);
      acc[i] = __builtin_amdgcn_mfma_f32_16x16x32_bf16(a1, b1, acc[i], 0,0,0);
    }

    // epilogue: lane's channels are {16i + quad*4 + r}
    float ph[8] = {0.f,0.f,0.f,0.f,0.f,0.f,0.f,0.f};
    #pragma unroll
    for (int i=0;i<16;++i){
      uint2 xlv = *(const uint2*)&xlr[(size_t)sn*512 +       i*16 + quad*4];
      uint2 xrv = *(const uint2*)&xlr[(size_t)dn*512 + 256 + i*16 + quad*4];
      float4 av = *(const float4*)&satt[i*16 + quad*4];
      float m0 = acc[i][0] + bfu((u16)(xlv.x & 0xffff)) + bfu((u16)(xrv.x & 0xffff));
      float m1 = acc[i][1] + bfu((u16)(xlv.x >> 16))    + bfu((u16)(xrv.x >> 16));
      float m2 = acc[i][2] + bfu((u16)(xlv.y & 0xffff)) + bfu((u16)(xrv.y & 0xffff));
      float m3 = acc[i][3] + bfu((u16)(xlv.y >> 16))    + bfu((u16)(xrv.y >> 16));
      float g0 = fmaxf(m0, 0.2f*m0), g1 = fmaxf(m1, 0.2f*m1);
      float g2 = fmaxf(m2, 0.2f*m2), g3 = fmaxf(m3, 0.2f*m3);
      ph[i>>1] += av.x*g0 + av.y*g1 + av.z*g2 + av.w*g3;
    }
    #pragma unroll
    for (int h=0;h<8;++h){
      ph[h] += __shfl_xor(ph[h], 16);
      ph[h] += __shfl_xor(ph[h], 32);
    }
    if (quad == 0){
      float4 lo = {ph[0], ph[1], ph[2], ph[3]};
      float4 hi = {ph[4], ph[5], ph[6], ph[7]};
      *(float4*)&logits[(size_t)p*8]     = lo;
      *(float4*)&logits[(size_t)p*8 + 4] = hi;
    }
  }
}

// ---------------- one wave per node: max pre-pass + softmax-aggregate + bias + residual + LN1 ----------------
__global__ __launch_bounds__(256)
void k_aggln(const int* __restrict__ rowstart, const int* __restrict__ srcof,
             const float* __restrict__ logits, const u16* __restrict__ xlr, const float* __restrict__ xbuf,
             const void* __restrict__ gat_bias, const void* __restrict__ ln1g, const void* __restrict__ ln1b,
             size_t poff, float* __restrict__ hbuf, const int* __restrict__ dflag)
{
  int isbf = *dflag;
  int lane = threadIdx.x & 63, wid = threadIdx.x >> 6;
  int n = blockIdx.x*4 + wid;
  int s = rowstart[n], deg = rowstart[n+1] - s;
  int myh = lane >> 3;                       // head of channels 4*lane..+3

  // pass 1: per-head max, lane-parallel over positions (logits contiguous by pos)
  float m0=-3e38f,m1=-3e38f,m2=-3e38f,m3=-3e38f,m4=-3e38f,m5=-3e38f,m6=-3e38f,m7=-3e38f;
  for (int j = lane; j < deg; j += 64) {
    const float4* lp = (const float4*)&logits[(size_t)(s+j)*8];
    float4 a = lp[0], b = lp[1];
    m0=fmaxf(m0,a.x); m1=fmaxf(m1,a.y); m2=fmaxf(m2,a.z); m3=fmaxf(m3,a.w);
    m4=fmaxf(m4,b.x); m5=fmaxf(m5,b.y); m6=fmaxf(m6,b.z); m7=fmaxf(m7,b.w);
  }
  #pragma unroll
  for (int off=1; off<64; off<<=1) {
    m0=fmaxf(m0,__shfl_xor(m0,off)); m1=fmaxf(m1,__shfl_xor(m1,off));
    m2=fmaxf(m2,__shfl_xor(m2,off)); m3=fmaxf(m3,__shfl_xor(m3,off));
    m4=fmaxf(m4,__shfl_xor(m4,off)); m5=fmaxf(m5,__shfl_xor(m5,off));
    m6=fmaxf(m6,__shfl_xor(m6,off)); m7=fmaxf(m7,__shfl_xor(m7,off));
  }
  float mh = m0;
  if (myh==1) mh=m1; if (myh==2) mh=m2; if (myh==3) mh=m3;
  if (myh==4) mh=m4; if (myh==5) mh=m5; if (myh==6) mh=m6; if (myh==7) mh=m7;

  // pass 2: exp-weighted aggregation (no rescaling)
  float lrun = 0.f, a0=0.f, a1=0.f, a2=0.f, a3=0.f;
  for (int c0 = 0; c0 < deg; c0 += 64) {
    int idx = s + c0 + lane; if (idx >= ET) idx = ET-1;
    int sv = srcof[idx];
    int lim = min(64, deg - c0);
    for (int j = 0; j < lim; ++j) {
      int sn = __shfl(sv, j);
      float lg = logits[(size_t)(s + c0 + j)*8 + myh];
      float wv = __expf(lg - mh);
      uint2 xv = *(const uint2*)&xlr[(size_t)sn*512 + 4*lane];
      lrun += wv;
      a0 += wv*bfu((u16)(xv.x & 0xffff));
      a1 += wv*bfu((u16)(xv.x >> 16));
      a2 += wv*bfu((u16)(xv.y & 0xffff));
      a3 += wv*bfu((u16)(xv.y >> 16));
    }
  }
  float inv = 1.f/(lrun + 1e-16f);
  int c = 4*lane;
  float4 res = *(const float4*)&xbuf[(size_t)n*256 + c];
  float o0 = a0*inv + ldf(gat_bias, poff+c+0, isbf) + res.x;
  float o1 = a1*inv + ldf(gat_bias, poff+c+1, isbf) + res.y;
  float o2 = a2*inv + ldf(gat_bias, poff+c+2, isbf) + res.z;
  float o3 = a3*inv + ldf(gat_bias, poff+c+3, isbf) + res.w;

  float v = o0+o1+o2+o3;
  #pragma unroll
  for (int off=1; off<64; off<<=1) v += __shfl_xor(v, off);
  float mu = v * (1.f/256.f);
  float d0=o0-mu, d1=o1-mu, d2=o2-mu, d3=o3-mu;
  float v2 = d0*d0+d1*d1+d2*d2+d3*d3;
  #pragma unroll
  for (int off=1; off<64; off<<=1) v2 += __shfl_xor(v2, off);
  float wn = rsqrtf(v2*(1.f/256.f) + 1e-5f);
  float4 outv;
  outv.x = d0*wn*ldf(ln1g, poff+c+0, isbf) + ldf(ln1b, poff+c+0, isbf);
  outv.y = d1*wn*ldf(ln1g, poff+c+1, isbf) + ldf(ln1b, poff+c+1, isbf);
  outv.z = d2*wn*ldf(ln1g, poff+c+2, isbf) + ldf(ln1b, poff+c+2, isbf);
  outv.w = d3*wn*ldf(ln1g, poff+c+3, isbf) + ldf(ln1b, poff+c+3, isbf);
  *(float4*)&hbuf[(size_t)n*256 + c] = outv;
}

// ---------------- residual + LN2 -> xbuf ----------------
__global__ __launch_bounds__(256)
void k_ln_add(const float* __restrict__ a, const u16* __restrict__ b2,
              const void* __restrict__ gg, const void* __restrict__ bb, size_t poff,
              float* __restrict__ out, const int* __restrict__ dflag)
{
  int isbf = *dflag;
  int n = blockIdx.x, t = threadIdx.x;
  __shared__ float r[256];
  float x = a[(size_t)n*256 + t] + bfu(b2[(size_t)n*256 + t]);
  r[t] = x; __syncthreads();
  for (int st = 128; st > 0; st >>= 1) { if (t < st) r[t] += r[t+st]; __syncthreads(); }
  float mu = r[0] * (1.f/256.f);
  __syncthreads();
  float d = x - mu;
  r[t] = d*d; __syncthreads();
  for (int st = 128; st > 0; st >>= 1) { if (t < st) r[t] += r[t+st]; __syncthreads(); }
  float var = r[0] * (1.f/256.f);
  out[(size_t)n*256 + t] = d * rsqrtf(var + 1e-5f) * ldf(gg, poff + t, isbf) + ldf(bb, poff + t, isbf);
}

__global__ void k_out(const float* __restrict__ x, void* __restrict__ out, const int* __restrict__ dflag)
{
  int isbf = *dflag;
  int i = blockIdx.x*256 + threadIdx.x;
  if (isbf) ((u16*)out)[i] = f2bf(x[i]);
  else      ((float*)out)[i] = x[i];
}

extern "C" void kernel_launch(void* const* d_in, const int* in_sizes, int n_in,
                              void* d_out, int out_size, void* d_ws, size_t ws_size,
                              hipStream_t stream)
{
  const void* node_feats = d_in[0];
  const int*  edge_index = (const int*)d_in[1];
  const void* edge_attr  = d_in[2];
  const void* init_node_w= d_in[3];
  const void* init_edge_w= d_in[4];
  const void* lin_l_w    = d_in[5];
  const void* lin_l_b    = d_in[6];
  const void* lin_r_w    = d_in[7];
  const void* lin_r_b    = d_in[8];
  const void* lin_edge_w = d_in[9];
  const void* att        = d_in[10];
  const void* gat_bias   = d_in[11];
  const void* ln1_g      = d_in[12];
  const void* ln1_b      = d_in[13];
  const void* mlp_w1     = d_in[14];
  const void* mlp_w2     = d_in[15];
  const void* ln2_g      = d_in[16];
  const void* ln2_b      = d_in[17];

  const int* srcp = edge_index;
  const int* dstp = edge_index + EE;

  char* p = (char*)d_ws;
  auto alloc = [&](size_t bytes) { void* r = (void*)p; p += (bytes + 255) & ~(size_t)255; return r; };
  int*   dflag   = (int*)alloc(256);
  int*   deg     = (int*)alloc((size_t)NN*4);
  int*   rowstart= (int*)alloc((size_t)(NN+1)*4);
  int*   fill    = (int*)alloc((size_t)NN*4);
  int*   csr     = (int*)alloc((size_t)ET*4);
  int*   srcof   = (int*)alloc((size_t)ET*4);
  int*   dstof   = (int*)alloc((size_t)ET*4);
  u16*   Wcb     = (u16*)alloc((size_t)2*256*64*2);
  u16*   loopmean= (u16*)alloc((size_t)NN*64*2);
  float* logits  = (float*)alloc((size_t)ET*8*4);
  float* xbuf    = (float*)alloc((size_t)NN*256*4);
  float* hbuf    = (float*)alloc((size_t)NN*256*4);
  u16*   xlr     = (u16*)alloc((size_t)NN*512*2);  // xl = cols 0..255, xr = cols 256..511
  u16*   ymid    = xlr;             // [NN,512] bf16 alias (xlr dead at MLP time)
  u16*   y2      = (u16*)d_out;     // bf16 scratch; final k_out overwrites

  hipMemsetAsync(deg,  0, (size_t)NN*4, stream);
  hipMemsetAsync(fill, 0, (size_t)NN*4, stream);

  k_detect <<<1, 256, 0, stream>>>(node_feats, dflag);

  k_count  <<<(ET+255)/256, 256, 0, stream>>>(dstp, deg);
  k_scan   <<<1, 256, 0, stream>>>(deg, rowstart);
  k_scatter<<<(ET+255)/256, 256, 0, stream>>>(dstp, srcp, rowstart, fill, csr, srcof, dstof);
  k_loopmean<<<NN, 64, 0, stream>>>(csr, rowstart, edge_attr, loopmean, dflag);
  k_wc     <<<128, 256, 0, stream>>>(lin_edge_w, init_edge_w, Wcb, dflag);

  // x = node_feats @ init_node_w.T  (fp32 out)
  mfma_gemm<0,0><<<dim3(2,128), 256, 0, stream>>>(node_feats, 2, init_node_w, 0, init_node_w, 0, 1<<29,
                                                  nullptr, nullptr, 0, 0, xbuf, NN, 256, 768, dflag);

  for (int l = 0; l < 2; ++l) {
    size_t wo = (size_t)l*256*256;
    size_t bo = (size_t)l*256;
    // xlr = [x@Wl^T + bl | x@Wr^T + br]  (dual-B, N=512)
    mfma_gemm<0,1><<<dim3(4,128), 256, 0, stream>>>(xbuf, 0, lin_l_w, wo, lin_r_w, wo, 256,
                                                    lin_l_b, lin_r_b, bo, 1, xlr, NN, 512, 256, dflag);
    k_elogits<<<1088, 256, 0, stream>>>(csr, srcof, dstof, Wcb + (size_t)l*256*64, xlr,
                                        edge_attr, loopmean, att, (size_t)l*256, logits, dflag);
    k_aggln<<<NN/4, 256, 0, stream>>>(rowstart, srcof, logits, xlr, xbuf,
                                      gat_bias, ln1_g, ln1_b, bo, hbuf, dflag);
    mfma_gemm<1,1><<<dim3(4,128), 256, 0, stream>>>(hbuf, 0, mlp_w1, (size_t)l*512*256, mlp_w1, 0, 1<<29,
                                                    nullptr, nullptr, 0, 0, ymid, NN, 512, 256, dflag);
    mfma_gemm<0,1><<<dim3(2,128), 256, 0, stream>>>(ymid, 1, mlp_w2, (size_t)l*256*512, mlp_w2, 0, 1<<29,
                                                    nullptr, nullptr, 0, 0, y2, NN, 256, 512, dflag);
    k_ln_add<<<NN, 256, 0, stream>>>(hbuf, y2, ln2_g, ln2_b, bo, xbuf, dflag);
  }

  k_out<<<(NN*256)/256, 256, 0, stream>>>(xbuf, d_out, dflag);
}